// Round 1
// baseline (776.584 us; speedup 1.0000x reference)
//
#include <hip/hip_runtime.h>
#include <stdint.h>

#define XD 1024
#define NS 65536
#define SPB 32
#define N1 256
#define N2 64

#if __has_builtin(__builtin_amdgcn_exp2f)
#define EXP2F(x) __builtin_amdgcn_exp2f(x)
#else
#define EXP2F(x) exp2f(x)
#endif
#if __has_builtin(__builtin_amdgcn_logf)
#define LOG2F(x) __builtin_amdgcn_logf(x)
#else
#define LOG2F(x) log2f(x)
#endif
#if __has_builtin(__builtin_amdgcn_rcpf)
#define RCPF(x) __builtin_amdgcn_rcpf(x)
#else
#define RCPF(x) (1.0f/(x))
#endif

typedef __attribute__((ext_vector_type(8))) short short8;
typedef __attribute__((ext_vector_type(4))) float float4v;

#define LOG2E 1.4426950408889634f
#define LN2   0.6931471805599453f
// -log2(ln2)
#define NL2LN2 0.5287663729448977f

static __device__ __forceinline__ float tanh_fast(float x){
  float e = EXP2F(x * 2.8853900817779268f);   // e^(2x)
  return (e - 1.0f) * RCPF(e + 1.0f);
}
static __device__ __forceinline__ unsigned short f2bf(float x){
  union { float f; uint32_t u; } c; c.f = x;
  uint32_t u = c.u;
  return (unsigned short)((u + 0x7FFFu + ((u >> 16) & 1u)) >> 16);
}

// log2(j!) for j=0..19
#define G2TAB_INIT {0.0f,0.0f,1.0f,2.5849625007f,4.5849625007f,6.9068905956f, \
  9.4918530963f,12.2992080189f,15.2992080189f,18.4691332114f,21.7910613063f, \
  25.2504929251f,28.8354554258f,32.5358951439f,36.3432500660f,40.2501406616f, \
  44.2501406616f,48.3376035030f,52.5075285040f,56.7554560173f}

// Pack W3 (fp32 [64][1024]) into bf16 MFMA B-fragment order:
// frag index = ((mat*64 + cc)*2 + kh)*64 + lane, 8 bf16 each,
// element j -> B[k = kh*32 + (lane>>4)*8 + j][col = cc*16 + (lane&15)]
__global__ void pack_w3(const float* __restrict__ W3r, const float* __restrict__ W3v,
                        unsigned short* __restrict__ pk){
  int tid = blockIdx.x * 256 + threadIdx.x;   // 0..16383
  int mat  = tid >> 13;
  int cc   = (tid >> 7) & 63;
  int kh   = (tid >> 6) & 1;
  int l    = tid & 63;
  int quad = l >> 4;
  int col  = cc * 16 + (l & 15);
  const float* W3 = mat ? W3v : W3r;
  int kbase = kh * 32 + quad * 8;
  unsigned short t[8];
  #pragma unroll
  for (int j = 0; j < 8; ++j) t[j] = f2bf(W3[(size_t)(kbase + j) * XD + col]);
  uint4 val;
  val.x = (uint32_t)t[0] | ((uint32_t)t[1] << 16);
  val.y = (uint32_t)t[2] | ((uint32_t)t[3] << 16);
  val.z = (uint32_t)t[4] | ((uint32_t)t[5] << 16);
  val.w = (uint32_t)t[6] | ((uint32_t)t[7] << 16);
  *(uint4*)(pk + (size_t)tid * 8) = val;
}

__global__ __launch_bounds__(256) void cmp_fused(
    const float* __restrict__ w,   const float* __restrict__ data,
    const float* __restrict__ W1r, const float* __restrict__ b1r,
    const float* __restrict__ W2r, const float* __restrict__ b2r,
    const float* __restrict__ b3r,
    const float* __restrict__ W1v, const float* __restrict__ b1v,
    const float* __restrict__ W2v, const float* __restrict__ b2v,
    const float* __restrict__ b3v,
    const unsigned short* __restrict__ w3pk,
    float* __restrict__ out)
{
  __shared__ float wtile[SPB][32];
  __shared__ float h1[SPB * N1];
  __shared__ __align__(16) unsigned short h2lds[2][SPB * 72]; // stride 72 bf16 (pad +8)
  __shared__ float lgf2[20];
  __shared__ float redbuf[SPB];

  const float G2tab[20] = G2TAB_INIT;

  int tid = threadIdx.x;
  int s0  = blockIdx.x * SPB;

  if (tid < 20)  lgf2[tid] = G2tab[tid];
  if (tid < SPB) redbuf[tid] = 0.0f;
  #pragma unroll
  for (int i = 0; i < 4; ++i)
    ((float*)wtile)[tid + 256 * i] = w[(size_t)s0 * 32 + tid + 256 * i];
  __syncthreads();

  // ---------------- phase 1: MLP layers 1-2 (fp32) ----------------
  for (int mat = 0; mat < 2; ++mat){
    const float* W1 = mat ? W1v : W1r;
    const float* b1 = mat ? b1v : b1r;
    const float* W2 = mat ? W2v : W2r;
    const float* b2 = mat ? b2v : b2r;
    // layer1: thread = output unit u (256 units), loop over 32 samples
    {
      int u = tid;
      float w1reg[16];
      #pragma unroll
      for (int k = 0; k < 16; ++k) w1reg[k] = W1[k * N1 + u];
      float bu = b1[u];
      int c0 = mat ? 2 : 0;   // rate uses w chunks {0,1,4,5}; v uses {2,3,6,7}
      for (int s = 0; s < SPB; ++s){
        const float4v* wr = (const float4v*)&wtile[s][0];
        float4v a = wr[c0], b = wr[c0 + 1], c = wr[c0 + 4], d = wr[c0 + 5];
        float acc = bu;
        acc = fmaf(a.x, w1reg[0],  acc); acc = fmaf(a.y, w1reg[1],  acc);
        acc = fmaf(a.z, w1reg[2],  acc); acc = fmaf(a.w, w1reg[3],  acc);
        acc = fmaf(b.x, w1reg[4],  acc); acc = fmaf(b.y, w1reg[5],  acc);
        acc = fmaf(b.z, w1reg[6],  acc); acc = fmaf(b.w, w1reg[7],  acc);
        acc = fmaf(c.x, w1reg[8],  acc); acc = fmaf(c.y, w1reg[9],  acc);
        acc = fmaf(c.z, w1reg[10], acc); acc = fmaf(c.w, w1reg[11], acc);
        acc = fmaf(d.x, w1reg[12], acc); acc = fmaf(d.y, w1reg[13], acc);
        acc = fmaf(d.z, w1reg[14], acc); acc = fmaf(d.w, w1reg[15], acc);
        h1[s * N1 + u] = tanh_fast(acc);
      }
    }
    __syncthreads();
    // layer2: thread = (u2 = tid&63, sample-group = tid>>6 of 8 samples)
    {
      int u2 = tid & 63, sg = tid >> 6;
      float acc[8];
      float b2u = b2[u2];
      #pragma unroll
      for (int i = 0; i < 8; ++i) acc[i] = b2u;
      for (int k4 = 0; k4 < 64; ++k4){
        float wa = W2[(k4 * 4 + 0) * N2 + u2];
        float wb = W2[(k4 * 4 + 1) * N2 + u2];
        float wc = W2[(k4 * 4 + 2) * N2 + u2];
        float wd = W2[(k4 * 4 + 3) * N2 + u2];
        #pragma unroll
        for (int i = 0; i < 8; ++i){
          float4v hv = ((const float4v*)h1)[(sg * 8 + i) * 64 + k4];
          acc[i] = fmaf(hv.x, wa, fmaf(hv.y, wb, fmaf(hv.z, wc, fmaf(hv.w, wd, acc[i]))));
        }
      }
      #pragma unroll
      for (int i = 0; i < 8; ++i)
        h2lds[mat][(sg * 8 + i) * 72 + u2] = f2bf(tanh_fast(acc[i]));
    }
    __syncthreads();
  }

  // ---------------- phase 2: layer3 MFMA + elementwise + reduce ----------------
  int lane = tid & 63;
  int wv_id = tid >> 6;
  int quad = lane >> 4;
  int mrow = lane & 15;

  // A fragments: h2[sample][k], lane holds A[m=lane&15][k=quad*8+j]
  short8 af[2][2][2];   // [mat][sample-tile][k-half]
  #pragma unroll
  for (int mat = 0; mat < 2; ++mat)
    #pragma unroll
    for (int st = 0; st < 2; ++st)
      #pragma unroll
      for (int kh = 0; kh < 2; ++kh)
        af[mat][st][kh] = *(const short8*)&h2lds[mat][(st * 16 + mrow) * 72 + kh * 32 + quad * 8];

  float acc2[2][4] = {{0,0,0,0},{0,0,0,0}};   // log2-domain logpmf sums
  const short8* Bp = (const short8*)w3pk;

  for (int it = 0; it < 16; ++it){
    int cc = it * 4 + wv_id;              // 16-column chunk id
    short8 br0 = Bp[(size_t)((cc) * 2 + 0) * 64 + lane];
    short8 br1 = Bp[(size_t)((cc) * 2 + 1) * 64 + lane];
    short8 bv0 = Bp[(size_t)((64 + cc) * 2 + 0) * 64 + lane];
    short8 bv1 = Bp[(size_t)((64 + cc) * 2 + 1) * 64 + lane];
    int col = cc * 16 + mrow;
    float b3rc = b3r[col], b3vc = b3v[col];
    #pragma unroll
    for (int st = 0; st < 2; ++st){
      float4v cr = {0,0,0,0}, cv = {0,0,0,0};
      cr = __builtin_amdgcn_mfma_f32_16x16x32_bf16(af[0][st][0], br0, cr, 0, 0, 0);
      cr = __builtin_amdgcn_mfma_f32_16x16x32_bf16(af[0][st][1], br1, cr, 0, 0, 0);
      cv = __builtin_amdgcn_mfma_f32_16x16x32_bf16(af[1][st][0], bv0, cv, 0, 0, 0);
      cv = __builtin_amdgcn_mfma_f32_16x16x32_bf16(af[1][st][1], bv1, cv, 0, 0, 0);
      #pragma unroll
      for (int r = 0; r < 4; ++r){
        int row = st * 16 + quad * 4 + r;
        float d  = data[(size_t)(s0 + row) * XD + col];
        float yr = cr[r] + b3rc;
        float yv = cv[r] + b3vc;
        // L2 = -log2(softplus(yr)); softplus in log2 domain, numerically stable
        float er   = EXP2F(-fabsf(yr) * LOG2E);
        float spbr = fmaf(fmaxf(yr, 0.0f), LOG2E, LOG2F(1.0f + er));
        float L2   = NL2LN2 - LOG2F(spbr);
        float ev   = EXP2F(-fabsf(yv) * LOG2E);
        float spbv = fmaf(fmaxf(yv, 0.0f), LOG2E, LOG2F(1.0f + ev));
        float v    = spbv * LN2;            // natural softplus
        // Z = sum_j 2^(j*L2 - v*log2(j!))
        float Z = 1.0f;
        float jL = L2;
        #pragma unroll
        for (int j = 1; j < 20; ++j){
          Z += EXP2F(fmaf(-v, G2tab[j], jL));
          jL += L2;
        }
        float log2Z = LOG2F(Z);
        int di = (int)d;
        // log2-scaled logpmf: d*L2 - v*log2(d!) - log2Z
        acc2[st][r] += fmaf(d, L2, fmaf(-v, lgf2[di], -log2Z));
      }
    }
  }

  // reduce over the 16 lanes sharing a row, then across waves via LDS atomics
  #pragma unroll
  for (int st = 0; st < 2; ++st)
    #pragma unroll
    for (int r = 0; r < 4; ++r){
      float vsum = acc2[st][r];
      vsum += __shfl_xor(vsum, 1);
      vsum += __shfl_xor(vsum, 2);
      vsum += __shfl_xor(vsum, 4);
      vsum += __shfl_xor(vsum, 8);
      if (mrow == 0) atomicAdd(&redbuf[st * 16 + quad * 4 + r], vsum);
    }
  __syncthreads();
  if (tid < SPB) out[s0 + tid] = redbuf[tid] * (-LN2 / 1024.0f);
}

extern "C" void kernel_launch(void* const* d_in, const int* in_sizes, int n_in,
                              void* d_out, int out_size, void* d_ws, size_t ws_size,
                              hipStream_t stream){
  const float* w    = (const float*)d_in[0];
  const float* data = (const float*)d_in[1];
  const float* W1r  = (const float*)d_in[2];
  const float* b1r  = (const float*)d_in[3];
  const float* W2r  = (const float*)d_in[4];
  const float* b2r  = (const float*)d_in[5];
  const float* W3r  = (const float*)d_in[6];
  const float* b3r  = (const float*)d_in[7];
  const float* W1v  = (const float*)d_in[8];
  const float* b1v  = (const float*)d_in[9];
  const float* W2v  = (const float*)d_in[10];
  const float* b2v  = (const float*)d_in[11];
  const float* W3v  = (const float*)d_in[12];
  const float* b3v  = (const float*)d_in[13];
  unsigned short* pk = (unsigned short*)d_ws;   // 512 KB bf16 packed W3
  float* out = (float*)d_out;

  hipLaunchKernelGGL(pack_w3, dim3(64), dim3(256), 0, stream, W3r, W3v, pk);
  hipLaunchKernelGGL(cmp_fused, dim3(NS / SPB), dim3(256), 0, stream,
                     w, data, W1r, b1r, W2r, b2r, b3r,
                     W1v, b1v, W2v, b2v, b3v, pk, out);
}

// Round 2
// 538.511 us; speedup vs baseline: 1.4421x; 1.4421x over previous
//
#include <hip/hip_runtime.h>
#include <stdint.h>

#define XD 1024
#define NS 65536
#define SPB 32
#define N1 256
#define N2 64

#if __has_builtin(__builtin_amdgcn_exp2f)
#define EXP2F(x) __builtin_amdgcn_exp2f(x)
#else
#define EXP2F(x) exp2f(x)
#endif
#if __has_builtin(__builtin_amdgcn_logf)
#define LOG2F(x) __builtin_amdgcn_logf(x)
#else
#define LOG2F(x) log2f(x)
#endif
#if __has_builtin(__builtin_amdgcn_rcpf)
#define RCPF(x) __builtin_amdgcn_rcpf(x)
#else
#define RCPF(x) (1.0f/(x))
#endif

typedef __attribute__((ext_vector_type(8))) short short8;
typedef __attribute__((ext_vector_type(4))) float float4v;

#define LOG2E 1.4426950408889634f
#define LN2   0.6931471805599453f
#define NL2LN2 0.5287663729448977f

// pk layout (shorts): [0 .. 131071]   W3 B-frags (2 mats x 64 cc x 2 kh x 64 lanes x 8)
//                     [131072 .. ]    W2 B-frags (2 mats x 4 cw x 8 ks x 64 lanes x 8)
#define PK2_OFF 131072

static __device__ __forceinline__ float tanh_fast(float x){
  float e = EXP2F(x * 2.8853900817779268f);   // e^(2x)
  return (e - 1.0f) * RCPF(e + 1.0f);
}
static __device__ __forceinline__ unsigned short f2bf(float x){
  union { float f; uint32_t u; } c; c.f = x;
  uint32_t u = c.u;
  return (unsigned short)((u + 0x7FFFu + ((u >> 16) & 1u)) >> 16);
}

// log2(j!) for j=0..19
#define G2TAB_INIT {0.0f,0.0f,1.0f,2.5849625007f,4.5849625007f,6.9068905956f, \
  9.4918530963f,12.2992080189f,15.2992080189f,18.4691332114f,21.7910613063f, \
  25.2504929251f,28.8354554258f,32.5358951439f,36.3432500660f,40.2501406616f, \
  44.2501406616f,48.3376035030f,52.5075285040f,56.7554560173f}

// Pack W3 [64][1024] and W2 [256][64] (fp32 row-major) into bf16 MFMA B-frag order.
// B-frag for 16x16x32: element j -> B[k = ks*32 + (lane>>4)*8 + j][col]
__global__ void pack_weights(const float* __restrict__ W3r, const float* __restrict__ W3v,
                             const float* __restrict__ W2r, const float* __restrict__ W2v,
                             unsigned short* __restrict__ pk){
  int tid = blockIdx.x * 256 + threadIdx.x;   // 0..20479
  unsigned short t[8];
  if (tid < 16384){
    int mat  = tid >> 13;
    int cc   = (tid >> 7) & 63;
    int kh   = (tid >> 6) & 1;
    int l    = tid & 63;
    int col  = cc * 16 + (l & 15);
    const float* W3 = mat ? W3v : W3r;
    int kbase = kh * 32 + (l >> 4) * 8;
    #pragma unroll
    for (int j = 0; j < 8; ++j) t[j] = f2bf(W3[(size_t)(kbase + j) * XD + col]);
    uint4 val;
    val.x = (uint32_t)t[0] | ((uint32_t)t[1] << 16);
    val.y = (uint32_t)t[2] | ((uint32_t)t[3] << 16);
    val.z = (uint32_t)t[4] | ((uint32_t)t[5] << 16);
    val.w = (uint32_t)t[6] | ((uint32_t)t[7] << 16);
    *(uint4*)(pk + (size_t)tid * 8) = val;
  } else {
    int t2 = tid - 16384;                     // 0..4095
    int mat = t2 >> 11;
    int cw  = (t2 >> 9) & 3;
    int ks  = (t2 >> 6) & 7;
    int l   = t2 & 63;
    const float* W2 = mat ? W2v : W2r;
    int kbase = ks * 32 + (l >> 4) * 8;
    int col = cw * 16 + (l & 15);
    #pragma unroll
    for (int j = 0; j < 8; ++j) t[j] = f2bf(W2[(size_t)(kbase + j) * N2 + col]);
    uint4 val;
    val.x = (uint32_t)t[0] | ((uint32_t)t[1] << 16);
    val.y = (uint32_t)t[2] | ((uint32_t)t[3] << 16);
    val.z = (uint32_t)t[4] | ((uint32_t)t[5] << 16);
    val.w = (uint32_t)t[6] | ((uint32_t)t[7] << 16);
    *(uint4*)(pk + (size_t)(PK2_OFF) + (size_t)t2 * 8) = val;
  }
}

__global__ __launch_bounds__(256, 5) void cmp_fused(
    const float* __restrict__ w,   const float* __restrict__ data,
    const float* __restrict__ W1r, const float* __restrict__ b1r,
    const float* __restrict__ b2r, const float* __restrict__ b3r,
    const float* __restrict__ W1v, const float* __restrict__ b1v,
    const float* __restrict__ b2v, const float* __restrict__ b3v,
    const unsigned short* __restrict__ pk,
    float* __restrict__ out)
{
  __shared__ float wtile[SPB][32];
  // h1 bf16, stride 264 shorts (pad +8): row stride 528 B = 33x16B (aligned),
  // 36-word stride mod 32 = 4 -> b128 reads are 2-way bank aliased = free.
  __shared__ __align__(16) unsigned short h1lds[SPB * 264];
  __shared__ __align__(16) unsigned short h2lds[2][SPB * 72]; // stride 72 shorts (pad +8)
  __shared__ float lgf2[20];
  __shared__ float redbuf[SPB];

  const float G2tab[20] = G2TAB_INIT;

  int tid = threadIdx.x;
  int s0  = blockIdx.x * SPB;
  int lane = tid & 63;
  int wv_id = tid >> 6;
  int quad = lane >> 4;
  int mrow = lane & 15;

  if (tid < 20)  lgf2[tid] = G2tab[tid];
  if (tid < SPB) redbuf[tid] = 0.0f;
  #pragma unroll
  for (int i = 0; i < 4; ++i)
    ((float*)wtile)[tid + 256 * i] = w[(size_t)s0 * 32 + tid + 256 * i];
  __syncthreads();

  // ---------------- phase 1: MLP layers 1-2 ----------------
  const short8* B2p = (const short8*)(pk + PK2_OFF);
  for (int mat = 0; mat < 2; ++mat){
    const float* W1 = mat ? W1v : W1r;
    const float* b1 = mat ? b1v : b1r;
    const float* b2 = mat ? b2v : b2r;
    // layer1 (fp32 VALU): thread = output unit u (256), loop over 32 samples
    {
      int u = tid;
      float w1reg[16];
      #pragma unroll
      for (int k = 0; k < 16; ++k) w1reg[k] = W1[k * N1 + u];
      float bu = b1[u];
      int c0 = mat ? 2 : 0;   // rate uses w chunks {0,1,4,5}; v uses {2,3,6,7}
      for (int s = 0; s < SPB; ++s){
        const float4v* wr = (const float4v*)&wtile[s][0];
        float4v a = wr[c0], b = wr[c0 + 1], c = wr[c0 + 4], d = wr[c0 + 5];
        float acc = bu;
        acc = fmaf(a.x, w1reg[0],  acc); acc = fmaf(a.y, w1reg[1],  acc);
        acc = fmaf(a.z, w1reg[2],  acc); acc = fmaf(a.w, w1reg[3],  acc);
        acc = fmaf(b.x, w1reg[4],  acc); acc = fmaf(b.y, w1reg[5],  acc);
        acc = fmaf(b.z, w1reg[6],  acc); acc = fmaf(b.w, w1reg[7],  acc);
        acc = fmaf(c.x, w1reg[8],  acc); acc = fmaf(c.y, w1reg[9],  acc);
        acc = fmaf(c.z, w1reg[10], acc); acc = fmaf(c.w, w1reg[11], acc);
        acc = fmaf(d.x, w1reg[12], acc); acc = fmaf(d.y, w1reg[13], acc);
        acc = fmaf(d.z, w1reg[14], acc); acc = fmaf(d.w, w1reg[15], acc);
        h1lds[s * 264 + u] = f2bf(tanh_fast(acc));
      }
    }
    __syncthreads();
    // layer2 (MFMA): wave wv_id handles n-chunk cw = wv_id (16 units).
    // M=32 samples (2 tiles), K=256 (8 steps of 32).
    {
      int cw = wv_id;
      float4v acc[2] = {{0,0,0,0},{0,0,0,0}};
      #pragma unroll
      for (int ks = 0; ks < 8; ++ks){
        short8 bfr = B2p[(size_t)((mat * 4 + cw) * 8 + ks) * 64 + lane];
        #pragma unroll
        for (int st = 0; st < 2; ++st){
          short8 a = *(const short8*)&h1lds[(st * 16 + mrow) * 264 + ks * 32 + quad * 8];
          acc[st] = __builtin_amdgcn_mfma_f32_16x16x32_bf16(a, bfr, acc[st], 0, 0, 0);
        }
      }
      float b2n = b2[cw * 16 + mrow];
      #pragma unroll
      for (int st = 0; st < 2; ++st)
        #pragma unroll
        for (int r = 0; r < 4; ++r){
          int sample = st * 16 + quad * 4 + r;
          h2lds[mat][sample * 72 + cw * 16 + mrow] = f2bf(tanh_fast(acc[st][r] + b2n));
        }
    }
    __syncthreads();
  }

  // ---------------- phase 2: layer3 MFMA + elementwise + reduce ----------------
  // A fragments: h2[sample][k], lane holds A[m=lane&15][k=quad*8+j]
  short8 af[2][2][2];   // [mat][sample-tile][k-half]
  #pragma unroll
  for (int mat = 0; mat < 2; ++mat)
    #pragma unroll
    for (int st = 0; st < 2; ++st)
      #pragma unroll
      for (int kh = 0; kh < 2; ++kh)
        af[mat][st][kh] = *(const short8*)&h2lds[mat][(st * 16 + mrow) * 72 + kh * 32 + quad * 8];

  float acc2[2][4] = {{0,0,0,0},{0,0,0,0}};   // log2-domain logpmf sums
  const short8* Bp = (const short8*)pk;

  for (int it = 0; it < 16; ++it){
    int cc = it * 4 + wv_id;              // 16-column chunk id
    short8 br0 = Bp[(size_t)((cc) * 2 + 0) * 64 + lane];
    short8 br1 = Bp[(size_t)((cc) * 2 + 1) * 64 + lane];
    short8 bv0 = Bp[(size_t)((64 + cc) * 2 + 0) * 64 + lane];
    short8 bv1 = Bp[(size_t)((64 + cc) * 2 + 1) * 64 + lane];
    int col = cc * 16 + mrow;
    float b3rc = b3r[col], b3vc = b3v[col];
    #pragma unroll
    for (int st = 0; st < 2; ++st){
      float4v cr = {0,0,0,0}, cv = {0,0,0,0};
      cr = __builtin_amdgcn_mfma_f32_16x16x32_bf16(af[0][st][0], br0, cr, 0, 0, 0);
      cr = __builtin_amdgcn_mfma_f32_16x16x32_bf16(af[0][st][1], br1, cr, 0, 0, 0);
      cv = __builtin_amdgcn_mfma_f32_16x16x32_bf16(af[1][st][0], bv0, cv, 0, 0, 0);
      cv = __builtin_amdgcn_mfma_f32_16x16x32_bf16(af[1][st][1], bv1, cv, 0, 0, 0);
      #pragma unroll
      for (int r = 0; r < 4; ++r){
        int row = st * 16 + quad * 4 + r;
        float d  = data[(size_t)(s0 + row) * XD + col];
        float yr = cr[r] + b3rc;
        float yv = cv[r] + b3vc;
        // L2 = -log2(softplus(yr)); softplus in log2 domain, numerically stable
        float er   = EXP2F(-fabsf(yr) * LOG2E);
        float spbr = fmaf(fmaxf(yr, 0.0f), LOG2E, LOG2F(1.0f + er));
        float L2   = NL2LN2 - LOG2F(spbr);
        float ev   = EXP2F(-fabsf(yv) * LOG2E);
        float spbv = fmaf(fmaxf(yv, 0.0f), LOG2E, LOG2F(1.0f + ev));
        float v    = spbv * LN2;            // natural softplus
        // Z = sum_j 2^(j*L2 - v*log2(j!))
        float Z = 1.0f;
        float jL = L2;
        #pragma unroll
        for (int j = 1; j < 20; ++j){
          Z += EXP2F(fmaf(-v, G2tab[j], jL));
          jL += L2;
        }
        float log2Z = LOG2F(Z);
        int di = (int)d;
        // log2-scaled logpmf: d*L2 - v*log2(d!) - log2Z
        acc2[st][r] += fmaf(d, L2, fmaf(-v, lgf2[di], -log2Z));
      }
    }
  }

  // reduce over the 16 lanes sharing a row, then across waves via LDS atomics
  #pragma unroll
  for (int st = 0; st < 2; ++st)
    #pragma unroll
    for (int r = 0; r < 4; ++r){
      float vsum = acc2[st][r];
      vsum += __shfl_xor(vsum, 1);
      vsum += __shfl_xor(vsum, 2);
      vsum += __shfl_xor(vsum, 4);
      vsum += __shfl_xor(vsum, 8);
      if (mrow == 0) atomicAdd(&redbuf[st * 16 + quad * 4 + r], vsum);
    }
  __syncthreads();
  if (tid < SPB) out[s0 + tid] = redbuf[tid] * (-LN2 / 1024.0f);
}

extern "C" void kernel_launch(void* const* d_in, const int* in_sizes, int n_in,
                              void* d_out, int out_size, void* d_ws, size_t ws_size,
                              hipStream_t stream){
  const float* w    = (const float*)d_in[0];
  const float* data = (const float*)d_in[1];
  const float* W1r  = (const float*)d_in[2];
  const float* b1r  = (const float*)d_in[3];
  const float* W2r  = (const float*)d_in[4];
  const float* b2r  = (const float*)d_in[5];
  const float* W3r  = (const float*)d_in[6];
  const float* b3r  = (const float*)d_in[7];
  const float* W1v  = (const float*)d_in[8];
  const float* b1v  = (const float*)d_in[9];
  const float* W2v  = (const float*)d_in[10];
  const float* b2v  = (const float*)d_in[11];
  const float* W3v  = (const float*)d_in[12];
  const float* b3v  = (const float*)d_in[13];
  unsigned short* pk = (unsigned short*)d_ws;   // 256KB W3 frags + 64KB W2 frags
  float* out = (float*)d_out;

  hipLaunchKernelGGL(pack_weights, dim3(80), dim3(256), 0, stream, W3r, W3v, W2r, W2v, pk);
  hipLaunchKernelGGL(cmp_fused, dim3(NS / SPB), dim3(256), 0, stream,
                     w, data, W1r, b1r, b2r, b3r,
                     W1v, b1v, b2v, b3v, pk, out);
}